// Round 13
// baseline (99.783 us; speedup 1.0000x reference)
//
#include <hip/hip_runtime.h>

#define N_NODES_C 50000
#define F_IN_C 64
#define HID_C 128
#define N_GRAPHS_C 500
#define N_CLS_C 10
#define MLP_HID_C 50
#define SCAN_TILE 1024
#define N_SCAN_BLK ((N_NODES_C + SCAN_TILE - 1) / SCAN_TILE)   // 49
#define N_TILES (N_NODES_C / 16)                               // 3125
#define N_RANGES 8
#define RANGE_SZ (N_NODES_C / N_RANGES)                        // 6250 (exact)
#define S_STRIPES 64
#define ZROW N_NODES_C                                         // zero row in xh
#define PAD_M 32                                               // adj pad granule

using short8 = __attribute__((ext_vector_type(8))) short;
using f32x4  = __attribute__((ext_vector_type(4))) float;

__device__ __forceinline__ int bl_i(int v, int l) {
    return __builtin_amdgcn_readlane(v, l);
}
__device__ __forceinline__ float uf(unsigned u) { return __uint_as_float(u); }

// round-to-nearest-even bf16 pack of two floats -> (lo=a, hi=b)
__device__ __forceinline__ unsigned pk_bf16(float a, float b) {
    unsigned ua = __float_as_uint(a), ub = __float_as_uint(b);
    ua += 0x7FFFu + ((ua >> 16) & 1u);
    ub += 0x7FFFu + ((ub >> 16) & 1u);
    return (ua >> 16) | (ub & 0xFFFF0000u);
}

union U8 { unsigned u[4]; uint4 q; short8 s; };

// ---------------------------------------------------------------------------
// Prep: bf16-compress x (+ zero row) + graph bounds + ZROW-fill padded adj.
// ---------------------------------------------------------------------------
__global__ __launch_bounds__(256) void prep_kernel(
    const float* __restrict__ x,
    const int* __restrict__ batch,
    unsigned* __restrict__ xh,
    int* __restrict__ start,
    int* __restrict__ adj,
    int adj_cap)
{
    int tid = blockIdx.x * 256 + threadIdx.x;
    int stride = gridDim.x * 256;
    const float2* xf2 = (const float2*)x;
    int nx = N_NODES_C * (F_IN_C / 2);
    int total = (N_NODES_C + 1) * (F_IN_C / 2);
    for (int i = tid; i < total; i += stride) {
        if (i < nx) { float2 v = xf2[i]; xh[i] = pk_bf16(v.x, v.y); }
        else        xh[i] = 0u;
    }
    for (int i = tid; i < adj_cap; i += stride) adj[i] = ZROW;
    for (int i = tid; i < N_NODES_C; i += stride) {
        int b = batch[i];
        if (i == 0) { for (int g = 0; g <= b; ++g) start[g] = 0; }
        else { int p = batch[i - 1]; for (int g = p + 1; g <= b; ++g) start[g] = i; }
        if (i == N_NODES_C - 1) { for (int g = b + 1; g <= N_GRAPHS_C; ++g) start[g] = N_NODES_C; }
    }
}

// ---------------------------------------------------------------------------
// hist2d: block (s,r) builds an LDS histogram of node-range r over edge-
// stripe s. No global atomics. Grid 512 = 2 blocks/CU.
// ---------------------------------------------------------------------------
__global__ __launch_bounds__(1024) void hist2d_kernel(
    const int* __restrict__ dst, int* __restrict__ h, int n_edges, int stripe)
{
    __shared__ int lh[RANGE_SZ];
    int s = blockIdx.x >> 3, r = blockIdx.x & 7;
    int lo = r * RANGE_SZ;
    int t = threadIdx.x;
    for (int i = t; i < RANGE_SZ; i += 1024) lh[i] = 0;
    __syncthreads();
    int e1 = min(n_edges, (s + 1) * stripe);
    for (int e = s * stripe + t; e < e1; e += 1024) {
        int d = dst[e] - lo;
        if ((unsigned)d < (unsigned)RANGE_SZ) atomicAdd(&lh[d], 1);
    }
    __syncthreads();
    for (int i = t; i < RANGE_SZ; i += 1024)
        h[(size_t)s * N_NODES_C + lo + i] = lh[i];
}

// ---------------------------------------------------------------------------
// reduce (+ fused scan1): per node, exclusive prefix over stripe counts ->
// p[s][n] (real); total -> deg_i[n] (real); PADDED per-tile sums -> bsums.
// ---------------------------------------------------------------------------
__global__ __launch_bounds__(1024) void reduce_kernel(
    const int* __restrict__ h, int* __restrict__ p, int* __restrict__ deg_i,
    int* __restrict__ bsums)
{
    __shared__ int sred[1024];
    int t = threadIdx.x;
    int n = blockIdx.x * 1024 + t;
    int run = 0;
    if (n < N_NODES_C) {
        #pragma unroll 8
        for (int s = 0; s < S_STRIPES; ++s) {
            int c = h[(size_t)s * N_NODES_C + n];
            p[(size_t)s * N_NODES_C + n] = run;
            run += c;
        }
        deg_i[n] = run;
    }
    sred[t] = (n < N_NODES_C) ? ((run + PAD_M - 1) & ~(PAD_M - 1)) : 0;
    __syncthreads();
    for (int o = 512; o > 0; o >>= 1) {
        if (t < o) sred[t] += sred[t + o];
        __syncthreads();
    }
    if (t == 0) bsums[blockIdx.x] = sred[0];
}

// scan3: tile-prefix via wave-reduce of bsums + intra-tile exclusive scan of
// PADDED degrees -> off[] (padded CSR offsets).
__global__ __launch_bounds__(256) void scan3_kernel(
    const int* __restrict__ deg_i, const int* __restrict__ bsums,
    int* __restrict__ off, int n)
{
    __shared__ int s[256];
    __shared__ int sbp;
    int b = blockIdx.x;
    int t = threadIdx.x;
    if (t < 64) {
        int v = (t < b) ? bsums[t] : 0;      // b <= 48 < 64
        #pragma unroll
        for (int m = 1; m < 64; m <<= 1) v += __shfl_xor(v, m, 64);
        if (t == 0) sbp = v;
    }
    int base = b * SCAN_TILE;
    int v4[4];
    int sum = 0;
    #pragma unroll
    for (int j = 0; j < 4; ++j) {
        int i = base + t * 4 + j;
        v4[j] = (i < n) ? ((deg_i[i] + PAD_M - 1) & ~(PAD_M - 1)) : 0;
        sum += v4[j];
    }
    s[t] = sum;
    __syncthreads();
    for (int o = 1; o < 256; o <<= 1) {
        int tmp = (t >= o) ? s[t - o] : 0;
        __syncthreads();
        s[t] += tmp;
        __syncthreads();
    }
    int run = s[t] - sum + sbp;
    #pragma unroll
    for (int j = 0; j < 4; ++j) {
        int i = base + t * 4 + j;
        if (i < n) off[i] = run;
        run += v4[j];
    }
    if (b == N_SCAN_BLK - 1 && t == 255) off[n] = sbp + s[255];
}

// ---------------------------------------------------------------------------
// scatter2d: block (s,r) places stripe-s edges of range r via LDS cursors
// seeded with off[d] + p[s][d]. Unique slots -> plain stores, no global
// atomics. Pad slots [off+deg, off+dpad) keep their ZROW pre-fill.
// ---------------------------------------------------------------------------
__global__ __launch_bounds__(1024) void scatter2d_kernel(
    const int* __restrict__ src, const int* __restrict__ dst,
    const int* __restrict__ off, const int* __restrict__ p,
    int* __restrict__ adj, int n_edges, int stripe)
{
    __shared__ int lcur[RANGE_SZ];
    int s = blockIdx.x >> 3, r = blockIdx.x & 7;
    int lo = r * RANGE_SZ;
    int t = threadIdx.x;
    for (int i = t; i < RANGE_SZ; i += 1024)
        lcur[i] = off[lo + i] + p[(size_t)s * N_NODES_C + lo + i];
    __syncthreads();
    int e1 = min(n_edges, (s + 1) * stripe);
    for (int e = s * stripe + t; e < e1; e += 1024) {
        int d = dst[e] - lo;
        if ((unsigned)d < (unsigned)RANGE_SZ) {
            int pos = atomicAdd(&lcur[d], 1);
            adj[pos] = src[e];
        }
    }
}

// ---------------------------------------------------------------------------
// Gather-mean: one node per wave; padded CSR -> branch-free 32-edge blocks =
// 16 independent 128B row loads in flight. Lanes 0-31 = even edge row,
// 32-63 = odd edge row; pad edges hit the ZROW line (broadcast, ~free).
// ---------------------------------------------------------------------------
__global__ __launch_bounds__(256) void gather_mean_kernel(
    const unsigned* __restrict__ xh,
    const int* __restrict__ adj,
    const int* __restrict__ off,
    const int* __restrict__ deg_i,
    unsigned* __restrict__ agg)
{
    int t = threadIdx.x;
    int wave = t >> 6, lane = t & 63;
    int node = blockIdx.x * 4 + wave;     // 12500 blocks * 4 = 50000 exact
    int o = off[node];
    int d = deg_i[node];
    int dpad = (d + PAD_M - 1) & ~(PAD_M - 1);
    int half = lane >> 5, col = lane & 31;
    float sx = 0.f, sy = 0.f;

    for (int j0 = 0; j0 < dpad; j0 += 64) {
        int c = min(dpad - j0, 64);       // multiple of 32
        int nid = (lane < c) ? adj[o + j0 + lane] : ZROW;
        for (int j = 0; j < c; j += 32) {
            unsigned u[16];
            #pragma unroll
            for (int m = 0; m < 16; ++m) {
                int re = bl_i(nid, j + 2 * m);
                int ro = bl_i(nid, j + 2 * m + 1);
                int row = half ? ro : re;
                u[m] = xh[(size_t)row * 32 + col];
            }
            #pragma unroll
            for (int m = 0; m < 16; ++m) {
                sx += uf(u[m] << 16); sy += uf(u[m] & 0xFFFF0000u);
            }
        }
    }
    sx += __shfl_xor(sx, 32, 64);
    sy += __shfl_xor(sy, 32, 64);
    if (half == 0) {
        float inv = 1.0f / fmaxf((float)d, 1.0f);
        agg[(size_t)node * 32 + col] = pk_bf16(sx * inv, sy * inv);
    }
}

// ---------------------------------------------------------------------------
// MFMA GEMM: emb = [x | agg] @ [[Ws],[Wn]] + b  (M=50000, K=128, N=128).
// W packed bf16-K-pairs in LDS ([64][129] u32, padded vs bank aliasing).
// ---------------------------------------------------------------------------
__global__ __launch_bounds__(256) void gemm_kernel(
    const unsigned* __restrict__ xh,
    const unsigned* __restrict__ agg,
    const float* __restrict__ Wn,
    const float* __restrict__ Ws,
    const float* __restrict__ bias,
    float* __restrict__ emb_out)
{
    __shared__ unsigned sWk[64 * 129];   // sWk[kk][n] = pack(Wf[2kk][n], Wf[2kk+1][n])
    __shared__ float sb[128];
    int t = threadIdx.x;
    for (int e = t; e < 64 * 128; e += 256) {
        int kk = e >> 7, n = e & 127;
        float w0, w1;
        if (kk < 32) { w0 = Ws[(2 * kk) * 128 + n];      w1 = Ws[(2 * kk + 1) * 128 + n]; }
        else         { w0 = Wn[(2 * kk - 64) * 128 + n]; w1 = Wn[(2 * kk - 63) * 128 + n]; }
        sWk[kk * 129 + n] = pk_bf16(w0, w1);
    }
    if (t < 128) sb[t] = bias[t];
    __syncthreads();

    int wave = t >> 6, lane = t & 63;
    int lr = lane & 15, lg = lane >> 4;
    int tile = blockIdx.x * 4 + wave;
    if (tile >= N_TILES) return;

    const uint4* xr = (const uint4*)(xh + ((size_t)tile * 16 + lr) * 32);
    const uint4* ar = (const uint4*)(agg + ((size_t)tile * 16 + lr) * 32);
    U8 A[4];
    A[0].q = xr[lg];
    A[1].q = xr[4 + lg];
    A[2].q = ar[lg];
    A[3].q = ar[4 + lg];

    #pragma unroll
    for (int c = 0; c < 8; ++c) {
        float bv = sb[c * 16 + lr];
        f32x4 acc = {bv, bv, bv, bv};
        #pragma unroll
        for (int s = 0; s < 4; ++s) {
            U8 B;
            #pragma unroll
            for (int jj = 0; jj < 4; ++jj)
                B.u[jj] = sWk[(16 * s + 4 * lg + jj) * 129 + c * 16 + lr];
            acc = __builtin_amdgcn_mfma_f32_16x16x32_bf16(A[s].s, B.s, acc, 0, 0, 0);
        }
        #pragma unroll
        for (int r = 0; r < 4; ++r)
            emb_out[((size_t)tile * 16 + lg * 4 + r) * 128 + c * 16 + lr] = acc[r];
    }
}

// ---------------------------------------------------------------------------
// Fused segment mean-pool of relu(emb) + MLP head + log_softmax.
// ---------------------------------------------------------------------------
__global__ __launch_bounds__(256) void poolhead_kernel(
    const float* __restrict__ emb, const int* __restrict__ start,
    const float* __restrict__ W1, const float* __restrict__ b1,
    const float* __restrict__ W2, const float* __restrict__ b2,
    float* __restrict__ logits_out)
{
    int g = blockIdx.x;
    int t = threadIdx.x;
    __shared__ float sp[HID_C];
    __shared__ float shid[MLP_HID_C];
    __shared__ float sl[N_CLS_C];
    __shared__ float4 red[256];

    int s0 = start[g], e0 = start[g + 1];
    int q = t & 31, r0 = t >> 5;
    const float4* e4 = (const float4*)emb;
    float4 acc = make_float4(0.f, 0.f, 0.f, 0.f);
    for (int r = s0 + r0; r < e0; r += 8) {
        float4 v = e4[(size_t)r * 32 + q];
        acc.x += fmaxf(v.x, 0.f); acc.y += fmaxf(v.y, 0.f);
        acc.z += fmaxf(v.z, 0.f); acc.w += fmaxf(v.w, 0.f);
    }
    red[t] = acc;
    __syncthreads();
    if (t < 32) {
        float4 a = red[t];
        #pragma unroll
        for (int r = 1; r < 8; ++r) {
            float4 b = red[t + 32 * r];
            a.x += b.x; a.y += b.y; a.z += b.z; a.w += b.w;
        }
        float inv = 1.0f / fmaxf((float)(e0 - s0), 1.0f);
        ((float4*)sp)[t] = make_float4(a.x * inv, a.y * inv, a.z * inv, a.w * inv);
    }
    __syncthreads();

    if (t < MLP_HID_C) {
        float a = b1[t];
        #pragma unroll 8
        for (int k = 0; k < HID_C; ++k) a += sp[k] * W1[k * MLP_HID_C + t];
        shid[t] = fmaxf(a, 0.0f);
    }
    __syncthreads();

    if (t < N_CLS_C) {
        float a = b2[t];
        #pragma unroll
        for (int k = 0; k < MLP_HID_C; ++k) a += shid[k] * W2[k * N_CLS_C + t];
        sl[t] = a;
    }
    __syncthreads();

    if (t < N_CLS_C) {
        float m = sl[0];
        #pragma unroll
        for (int i = 1; i < N_CLS_C; ++i) m = fmaxf(m, sl[i]);
        float sum = 0.0f;
        #pragma unroll
        for (int i = 0; i < N_CLS_C; ++i) sum += expf(sl[i] - m);
        logits_out[(size_t)g * N_CLS_C + t] = sl[t] - m - logf(sum);
    }
}

extern "C" void kernel_launch(void* const* d_in, const int* in_sizes, int n_in,
                              void* d_out, int out_size, void* d_ws, size_t ws_size,
                              hipStream_t stream) {
    const float* x      = (const float*)d_in[0];
    const int*   ei     = (const int*)d_in[1];
    const int*   batch  = (const int*)d_in[2];
    const float* Wn     = (const float*)d_in[3];
    const float* Ws     = (const float*)d_in[4];
    const float* bias   = (const float*)d_in[5];
    const float* W1     = (const float*)d_in[6];
    const float* b1     = (const float*)d_in[7];
    const float* W2     = (const float*)d_in[8];
    const float* b2     = (const float*)d_in[9];

    float* out = (float*)d_out;
    int n_edges = in_sizes[1] / 2;
    const int* src = ei;
    const int* dst = ei + n_edges;
    int stripe = (n_edges + S_STRIPES - 1) / S_STRIPES;
    int adj_cap = n_edges + (PAD_M - 1) * N_NODES_C;   // padded-CSR upper bound

    // ws (ints): deg_i[N] | off[N+1] | bsums[64] | start[G+1] | pad[2] |
    //            xh[(N+1)*32] | adj[adj_cap pad4] | agg[N*32] | h[S*N] | p[S*N]
    int* deg_i   = (int*)d_ws;
    int* off     = deg_i + N_NODES_C;
    int* bsums   = off + (N_NODES_C + 1);
    int* start   = bsums + 64;
    unsigned* xh = (unsigned*)(start + (N_GRAPHS_C + 1) + 2);   // 16B-aligned
    int* adj     = (int*)(xh + (size_t)(N_NODES_C + 1) * 32);
    unsigned* agg = (unsigned*)(adj + (((size_t)adj_cap + 3) & ~3ull));
    int* h       = (int*)(agg + (size_t)N_NODES_C * 32);
    int* p       = h + (size_t)S_STRIPES * N_NODES_C;

    prep_kernel<<<1024, 256, 0, stream>>>(x, batch, xh, start, adj, adj_cap);
    hist2d_kernel<<<S_STRIPES * N_RANGES, 1024, 0, stream>>>(dst, h, n_edges, stripe);
    reduce_kernel<<<N_SCAN_BLK, 1024, 0, stream>>>(h, p, deg_i, bsums);
    scan3_kernel<<<N_SCAN_BLK, 256, 0, stream>>>(deg_i, bsums, off, N_NODES_C);
    scatter2d_kernel<<<S_STRIPES * N_RANGES, 1024, 0, stream>>>(src, dst, off, p,
                                                                adj, n_edges, stripe);

    gather_mean_kernel<<<12500, 256, 0, stream>>>(xh, adj, off, deg_i, agg);

    gemm_kernel<<<782, 256, 0, stream>>>(xh, agg, Wn, Ws, bias, out);

    poolhead_kernel<<<N_GRAPHS_C, 256, 0, stream>>>(out, start, W1, b1, W2, b2,
                                                    out + (size_t)N_NODES_C * HID_C);
}

// Round 14
// 92.182 us; speedup vs baseline: 1.0825x; 1.0825x over previous
//
#include <hip/hip_runtime.h>

#define N_NODES_C 50000
#define F_IN_C 64
#define HID_C 128
#define N_GRAPHS_C 500
#define N_CLS_C 10
#define MLP_HID_C 50
#define SCAN_TILE 1024
#define N_SCAN_BLK ((N_NODES_C + SCAN_TILE - 1) / SCAN_TILE)   // 49
#define N_TILES (N_NODES_C / 16)                               // 3125
#define N_RANGES 8
#define RANGE_SZ (N_NODES_C / N_RANGES)                        // 6250 (exact)
#define S_STRIPES 64

using short8 = __attribute__((ext_vector_type(8))) short;
using f32x4  = __attribute__((ext_vector_type(4))) float;

__device__ __forceinline__ int bl_i(int v, int l) {
    return __builtin_amdgcn_readlane(v, l);
}
__device__ __forceinline__ float uf(unsigned u) { return __uint_as_float(u); }

// round-to-nearest-even bf16 pack of two floats -> (lo=a, hi=b)
__device__ __forceinline__ unsigned pk_bf16(float a, float b) {
    unsigned ua = __float_as_uint(a), ub = __float_as_uint(b);
    ua += 0x7FFFu + ((ua >> 16) & 1u);
    ub += 0x7FFFu + ((ub >> 16) & 1u);
    return (ua >> 16) | (ub & 0xFFFF0000u);
}

union U8 { unsigned u[4]; uint4 q; short8 s; };

// ---------------------------------------------------------------------------
// hist2d + fused prep: block (s,r) = (blockIdx>>3, blockIdx&7) builds an LDS
// histogram of node-range r over edge-stripe s (no global atomics). Between
// the hist phases, the whole grid also streams the prep work (bf16-compress
// x + zero row, graph bounds) — hides prep under the edge scan.
// ---------------------------------------------------------------------------
__global__ __launch_bounds__(1024) void hist2d_kernel(
    const int* __restrict__ dst,
    const float* __restrict__ x,
    const int* __restrict__ batch,
    unsigned* __restrict__ xh,
    int* __restrict__ start,
    int* __restrict__ h,
    int n_edges, int stripe)
{
    __shared__ int lh[RANGE_SZ];
    int s = blockIdx.x >> 3, r = blockIdx.x & 7;
    int lo = r * RANGE_SZ;
    int t = threadIdx.x;
    for (int i = t; i < RANGE_SZ; i += 1024) lh[i] = 0;
    __syncthreads();
    int e1 = min(n_edges, (s + 1) * stripe);
    for (int e = s * stripe + t; e < e1; e += 1024) {
        int d = dst[e] - lo;
        if ((unsigned)d < (unsigned)RANGE_SZ) atomicAdd(&lh[d], 1);
    }

    // fused prep (grid-stride across all 512 blocks)
    int tid = blockIdx.x * 1024 + t;
    int stride = gridDim.x * 1024;
    const float2* xf2 = (const float2*)x;
    int nx = N_NODES_C * (F_IN_C / 2);
    int total = (N_NODES_C + 1) * (F_IN_C / 2);
    for (int i = tid; i < total; i += stride) {
        if (i < nx) { float2 v = xf2[i]; xh[i] = pk_bf16(v.x, v.y); }
        else        xh[i] = 0u;
    }
    for (int i = tid; i < N_NODES_C; i += stride) {
        int b = batch[i];
        if (i == 0) { for (int g = 0; g <= b; ++g) start[g] = 0; }
        else { int p = batch[i - 1]; for (int g = p + 1; g <= b; ++g) start[g] = i; }
        if (i == N_NODES_C - 1) { for (int g = b + 1; g <= N_GRAPHS_C; ++g) start[g] = N_NODES_C; }
    }

    __syncthreads();
    for (int i = t; i < RANGE_SZ; i += 1024)
        h[(size_t)s * N_NODES_C + lo + i] = lh[i];
}

// ---------------------------------------------------------------------------
// reduce (+ fused scan1): per node, exclusive prefix over stripe counts ->
// p[s][n]; total -> deg_i[n]; per-1024-tile sum -> bsums via LDS tree.
// ---------------------------------------------------------------------------
__global__ __launch_bounds__(1024) void reduce_kernel(
    const int* __restrict__ h, int* __restrict__ p, int* __restrict__ deg_i,
    int* __restrict__ bsums)
{
    __shared__ int sred[1024];
    int t = threadIdx.x;
    int n = blockIdx.x * 1024 + t;
    int run = 0;
    if (n < N_NODES_C) {
        #pragma unroll 8
        for (int s = 0; s < S_STRIPES; ++s) {
            int c = h[(size_t)s * N_NODES_C + n];
            p[(size_t)s * N_NODES_C + n] = run;
            run += c;
        }
        deg_i[n] = run;
    }
    sred[t] = (n < N_NODES_C) ? run : 0;
    __syncthreads();
    for (int o = 512; o > 0; o >>= 1) {
        if (t < o) sred[t] += sred[t + o];
        __syncthreads();
    }
    if (t == 0) bsums[blockIdx.x] = sred[0];
}

// scan3: tile-prefix via wave-reduce of bsums + intra-tile exclusive scan
__global__ __launch_bounds__(256) void scan3_kernel(
    const int* __restrict__ deg_i, const int* __restrict__ bsums,
    int* __restrict__ off, int n)
{
    __shared__ int s[256];
    __shared__ int sbp;
    int b = blockIdx.x;
    int t = threadIdx.x;
    if (t < 64) {
        int v = (t < b) ? bsums[t] : 0;      // b <= 48 < 64
        #pragma unroll
        for (int m = 1; m < 64; m <<= 1) v += __shfl_xor(v, m, 64);
        if (t == 0) sbp = v;
    }
    int base = b * SCAN_TILE;
    int v4[4];
    int sum = 0;
    #pragma unroll
    for (int j = 0; j < 4; ++j) {
        int i = base + t * 4 + j;
        v4[j] = (i < n) ? deg_i[i] : 0;
        sum += v4[j];
    }
    s[t] = sum;
    __syncthreads();
    for (int o = 1; o < 256; o <<= 1) {
        int tmp = (t >= o) ? s[t - o] : 0;
        __syncthreads();
        s[t] += tmp;
        __syncthreads();
    }
    int run = s[t] - sum + sbp;
    #pragma unroll
    for (int j = 0; j < 4; ++j) {
        int i = base + t * 4 + j;
        if (i < n) off[i] = run;
        run += v4[j];
    }
    if (b == N_SCAN_BLK - 1 && t == 255) off[n] = sbp + s[255];
}

// ---------------------------------------------------------------------------
// scatter2d: block (s,r) places stripe-s edges of range r via LDS cursors
// seeded with off[d] + p[s][d]. Unique slots -> plain stores, zero global
// atomics. Grid 512 = 2 blocks/CU.
// ---------------------------------------------------------------------------
__global__ __launch_bounds__(1024) void scatter2d_kernel(
    const int* __restrict__ src, const int* __restrict__ dst,
    const int* __restrict__ off, const int* __restrict__ p,
    int* __restrict__ adj, int n_edges, int stripe)
{
    __shared__ int lcur[RANGE_SZ];
    int s = blockIdx.x >> 3, r = blockIdx.x & 7;
    int lo = r * RANGE_SZ;
    int t = threadIdx.x;
    for (int i = t; i < RANGE_SZ; i += 1024)
        lcur[i] = off[lo + i] + p[(size_t)s * N_NODES_C + lo + i];
    __syncthreads();
    int e1 = min(n_edges, (s + 1) * stripe);
    for (int e = s * stripe + t; e < e1; e += 1024) {
        int d = dst[e] - lo;
        if ((unsigned)d < (unsigned)RANGE_SZ) {
            int pos = atomicAdd(&lcur[d], 1);
            adj[pos] = src[e];
        }
    }
}

// ---------------------------------------------------------------------------
// Gather-mean (round-11 proven form): one wave per node, TWO edges per load
// instr (lanes 0-31 = even edge row, 32-63 = odd edge row), 8-edge granule.
// Fold halves with one shfl_xor(32). Source = 6.4MB, ~L2-resident.
// ---------------------------------------------------------------------------
__global__ __launch_bounds__(256) void gather_mean_kernel(
    const unsigned* __restrict__ xh,
    const int* __restrict__ adj,
    const int* __restrict__ off,
    unsigned* __restrict__ agg)
{
    int t = threadIdx.x;
    int wave = t >> 6, lane = t & 63;
    int node = blockIdx.x * 4 + wave;     // 12500 blocks * 4 = 50000 exact
    int o = off[node];
    int d = off[node + 1] - o;
    int half = lane >> 5;
    int col = lane & 31;
    float sx = 0.f, sy = 0.f;

    for (int j0 = 0; j0 < d; j0 += 64) {
        int c = d - j0; if (c > 64) c = 64;
        int nid = (lane < c) ? adj[o + j0 + lane] : 0;
        int j = 0;
        for (; j + 8 <= c; j += 8) {
            #pragma unroll
            for (int m = 0; m < 4; ++m) {
                int re = bl_i(nid, j + 2 * m);
                int ro = bl_i(nid, j + 2 * m + 1);
                int row = half ? ro : re;
                unsigned u = xh[(size_t)row * 32 + col];
                sx += uf(u << 16); sy += uf(u & 0xFFFF0000u);
            }
        }
        for (; j < c; j += 2) {
            int re = bl_i(nid, j);
            int ro = (j + 1 < c) ? bl_i(nid, j + 1) : re;
            int row = half ? ro : re;
            unsigned u = xh[(size_t)row * 32 + col];
            if (half && j + 1 >= c) u = 0u;
            sx += uf(u << 16); sy += uf(u & 0xFFFF0000u);
        }
    }
    sx += __shfl_xor(sx, 32, 64);
    sy += __shfl_xor(sy, 32, 64);
    if (half == 0) {
        float inv = 1.0f / fmaxf((float)d, 1.0f);
        agg[(size_t)node * 32 + col] = pk_bf16(sx * inv, sy * inv);
    }
}

// ---------------------------------------------------------------------------
// MFMA GEMM: emb = [x | agg] @ [[Ws],[Wn]] + b  (M=50000, K=128, N=128).
// W packed bf16-K-pairs in LDS ([64][129] u32, padded vs bank aliasing).
// ---------------------------------------------------------------------------
__global__ __launch_bounds__(256) void gemm_kernel(
    const unsigned* __restrict__ xh,
    const unsigned* __restrict__ agg,
    const float* __restrict__ Wn,
    const float* __restrict__ Ws,
    const float* __restrict__ bias,
    float* __restrict__ emb_out)
{
    __shared__ unsigned sWk[64 * 129];   // sWk[kk][n] = pack(Wf[2kk][n], Wf[2kk+1][n])
    __shared__ float sb[128];
    int t = threadIdx.x;
    for (int e = t; e < 64 * 128; e += 256) {
        int kk = e >> 7, n = e & 127;
        float w0, w1;
        if (kk < 32) { w0 = Ws[(2 * kk) * 128 + n];      w1 = Ws[(2 * kk + 1) * 128 + n]; }
        else         { w0 = Wn[(2 * kk - 64) * 128 + n]; w1 = Wn[(2 * kk - 63) * 128 + n]; }
        sWk[kk * 129 + n] = pk_bf16(w0, w1);
    }
    if (t < 128) sb[t] = bias[t];
    __syncthreads();

    int wave = t >> 6, lane = t & 63;
    int lr = lane & 15, lg = lane >> 4;
    int tile = blockIdx.x * 4 + wave;
    if (tile >= N_TILES) return;

    const uint4* xr = (const uint4*)(xh + ((size_t)tile * 16 + lr) * 32);
    const uint4* ar = (const uint4*)(agg + ((size_t)tile * 16 + lr) * 32);
    U8 A[4];
    A[0].q = xr[lg];
    A[1].q = xr[4 + lg];
    A[2].q = ar[lg];
    A[3].q = ar[4 + lg];

    #pragma unroll
    for (int c = 0; c < 8; ++c) {
        float bv = sb[c * 16 + lr];
        f32x4 acc = {bv, bv, bv, bv};
        #pragma unroll
        for (int s = 0; s < 4; ++s) {
            U8 B;
            #pragma unroll
            for (int jj = 0; jj < 4; ++jj)
                B.u[jj] = sWk[(16 * s + 4 * lg + jj) * 129 + c * 16 + lr];
            acc = __builtin_amdgcn_mfma_f32_16x16x32_bf16(A[s].s, B.s, acc, 0, 0, 0);
        }
        #pragma unroll
        for (int r = 0; r < 4; ++r)
            emb_out[((size_t)tile * 16 + lg * 4 + r) * 128 + c * 16 + lr] = acc[r];
    }
}

// ---------------------------------------------------------------------------
// Fused segment mean-pool of relu(emb) + MLP head + log_softmax.
// ---------------------------------------------------------------------------
__global__ __launch_bounds__(256) void poolhead_kernel(
    const float* __restrict__ emb, const int* __restrict__ start,
    const float* __restrict__ W1, const float* __restrict__ b1,
    const float* __restrict__ W2, const float* __restrict__ b2,
    float* __restrict__ logits_out)
{
    int g = blockIdx.x;
    int t = threadIdx.x;
    __shared__ float sp[HID_C];
    __shared__ float shid[MLP_HID_C];
    __shared__ float sl[N_CLS_C];
    __shared__ float4 red[256];

    int s0 = start[g], e0 = start[g + 1];
    int q = t & 31, r0 = t >> 5;
    const float4* e4 = (const float4*)emb;
    float4 acc = make_float4(0.f, 0.f, 0.f, 0.f);
    for (int r = s0 + r0; r < e0; r += 8) {
        float4 v = e4[(size_t)r * 32 + q];
        acc.x += fmaxf(v.x, 0.f); acc.y += fmaxf(v.y, 0.f);
        acc.z += fmaxf(v.z, 0.f); acc.w += fmaxf(v.w, 0.f);
    }
    red[t] = acc;
    __syncthreads();
    if (t < 32) {
        float4 a = red[t];
        #pragma unroll
        for (int r = 1; r < 8; ++r) {
            float4 b = red[t + 32 * r];
            a.x += b.x; a.y += b.y; a.z += b.z; a.w += b.w;
        }
        float inv = 1.0f / fmaxf((float)(e0 - s0), 1.0f);
        ((float4*)sp)[t] = make_float4(a.x * inv, a.y * inv, a.z * inv, a.w * inv);
    }
    __syncthreads();

    if (t < MLP_HID_C) {
        float a = b1[t];
        #pragma unroll 8
        for (int k = 0; k < HID_C; ++k) a += sp[k] * W1[k * MLP_HID_C + t];
        shid[t] = fmaxf(a, 0.0f);
    }
    __syncthreads();

    if (t < N_CLS_C) {
        float a = b2[t];
        #pragma unroll
        for (int k = 0; k < MLP_HID_C; ++k) a += shid[k] * W2[k * N_CLS_C + t];
        sl[t] = a;
    }
    __syncthreads();

    if (t < N_CLS_C) {
        float m = sl[0];
        #pragma unroll
        for (int i = 1; i < N_CLS_C; ++i) m = fmaxf(m, sl[i]);
        float sum = 0.0f;
        #pragma unroll
        for (int i = 0; i < N_CLS_C; ++i) sum += expf(sl[i] - m);
        logits_out[(size_t)g * N_CLS_C + t] = sl[t] - m - logf(sum);
    }
}

extern "C" void kernel_launch(void* const* d_in, const int* in_sizes, int n_in,
                              void* d_out, int out_size, void* d_ws, size_t ws_size,
                              hipStream_t stream) {
    const float* x      = (const float*)d_in[0];
    const int*   ei     = (const int*)d_in[1];
    const int*   batch  = (const int*)d_in[2];
    const float* Wn     = (const float*)d_in[3];
    const float* Ws     = (const float*)d_in[4];
    const float* bias   = (const float*)d_in[5];
    const float* W1     = (const float*)d_in[6];
    const float* b1     = (const float*)d_in[7];
    const float* W2     = (const float*)d_in[8];
    const float* b2     = (const float*)d_in[9];

    float* out = (float*)d_out;
    int n_edges = in_sizes[1] / 2;
    const int* src = ei;
    const int* dst = ei + n_edges;
    int stripe = (n_edges + S_STRIPES - 1) / S_STRIPES;

    // ws (ints): deg_i[N] | off[N+1] | bsums[64] | start[G+1] | pad[2] |
    //            xh[(N+1)*32] | adj[E(pad4)] | agg[N*32] | h[S*N] | p[S*N]
    int* deg_i   = (int*)d_ws;
    int* off     = deg_i + N_NODES_C;
    int* bsums   = off + (N_NODES_C + 1);
    int* start   = bsums + 64;
    unsigned* xh = (unsigned*)(start + (N_GRAPHS_C + 1) + 2);   // 16B-aligned
    int* adj     = (int*)(xh + (size_t)(N_NODES_C + 1) * 32);
    unsigned* agg = (unsigned*)(adj + ((n_edges + 3) & ~3));
    int* h       = (int*)(agg + (size_t)N_NODES_C * 32);
    int* p       = h + (size_t)S_STRIPES * N_NODES_C;

    hist2d_kernel<<<S_STRIPES * N_RANGES, 1024, 0, stream>>>(dst, x, batch, xh,
                                                             start, h, n_edges, stripe);
    reduce_kernel<<<N_SCAN_BLK, 1024, 0, stream>>>(h, p, deg_i, bsums);
    scan3_kernel<<<N_SCAN_BLK, 256, 0, stream>>>(deg_i, bsums, off, N_NODES_C);
    scatter2d_kernel<<<S_STRIPES * N_RANGES, 1024, 0, stream>>>(src, dst, off, p,
                                                                adj, n_edges, stripe);

    gather_mean_kernel<<<12500, 256, 0, stream>>>(xh, adj, off, agg);

    gemm_kernel<<<782, 256, 0, stream>>>(xh, agg, Wn, Ws, bias, out);

    poolhead_kernel<<<N_GRAPHS_C, 256, 0, stream>>>(out, start, W1, b1, W2, b2,
                                                    out + (size_t)N_NODES_C * HID_C);
}

// Round 15
// 88.146 us; speedup vs baseline: 1.1320x; 1.0458x over previous
//
#include <hip/hip_runtime.h>

#define N_NODES_C 50000
#define F_IN_C 64
#define HID_C 128
#define N_GRAPHS_C 500
#define N_CLS_C 10
#define MLP_HID_C 50
#define SCAN_TILE 1024
#define N_SCAN_BLK ((N_NODES_C + SCAN_TILE - 1) / SCAN_TILE)   // 49
#define N_TILES (N_NODES_C / 16)                               // 3125
#define N_RANGES 8
#define RANGE_SZ (N_NODES_C / N_RANGES)                        // 6250 (exact)
#define S_STRIPES 64

using short8 = __attribute__((ext_vector_type(8))) short;
using f32x4  = __attribute__((ext_vector_type(4))) float;

__device__ __forceinline__ int bl_i(int v, int l) {
    return __builtin_amdgcn_readlane(v, l);
}
__device__ __forceinline__ float uf(unsigned u) { return __uint_as_float(u); }

// round-to-nearest-even bf16 pack of two floats -> (lo=a, hi=b)
__device__ __forceinline__ unsigned pk_bf16(float a, float b) {
    unsigned ua = __float_as_uint(a), ub = __float_as_uint(b);
    ua += 0x7FFFu + ((ua >> 16) & 1u);
    ub += 0x7FFFu + ((ub >> 16) & 1u);
    return (ua >> 16) | (ub & 0xFFFF0000u);
}

union U8 { unsigned u[4]; uint4 q; short8 s; };

// ---------------------------------------------------------------------------
// hist2d + fused prep: block (s,r) builds an LDS histogram of node-range r
// over edge-stripe s (no global atomics); h stored u16 (counts <= stripe).
// Between hist phases the grid streams prep (bf16 x + zero row, bounds).
// ---------------------------------------------------------------------------
__global__ __launch_bounds__(1024) void hist2d_kernel(
    const int* __restrict__ dst,
    const float* __restrict__ x,
    const int* __restrict__ batch,
    unsigned* __restrict__ xh,
    int* __restrict__ start,
    unsigned short* __restrict__ h,
    int n_edges, int stripe)
{
    __shared__ int lh[RANGE_SZ];
    int s = blockIdx.x >> 3, r = blockIdx.x & 7;
    int lo = r * RANGE_SZ;
    int t = threadIdx.x;
    for (int i = t; i < RANGE_SZ; i += 1024) lh[i] = 0;
    __syncthreads();
    int e1 = min(n_edges, (s + 1) * stripe);
    #pragma unroll 4
    for (int e = s * stripe + t; e < e1; e += 1024) {
        int d = dst[e] - lo;
        if ((unsigned)d < (unsigned)RANGE_SZ) atomicAdd(&lh[d], 1);
    }

    // fused prep (grid-stride across all 512 blocks)
    int tid = blockIdx.x * 1024 + t;
    int stride = gridDim.x * 1024;
    const float2* xf2 = (const float2*)x;
    int nx = N_NODES_C * (F_IN_C / 2);
    int total = (N_NODES_C + 1) * (F_IN_C / 2);
    for (int i = tid; i < total; i += stride) {
        if (i < nx) { float2 v = xf2[i]; xh[i] = pk_bf16(v.x, v.y); }
        else        xh[i] = 0u;
    }
    for (int i = tid; i < N_NODES_C; i += stride) {
        int b = batch[i];
        if (i == 0) { for (int g = 0; g <= b; ++g) start[g] = 0; }
        else { int p = batch[i - 1]; for (int g = p + 1; g <= b; ++g) start[g] = i; }
        if (i == N_NODES_C - 1) { for (int g = b + 1; g <= N_GRAPHS_C; ++g) start[g] = N_NODES_C; }
    }

    __syncthreads();
    for (int i = t; i < RANGE_SZ; i += 1024)
        h[(size_t)s * N_NODES_C + lo + i] = (unsigned short)lh[i];
}

// ---------------------------------------------------------------------------
// reduce (+ fused scan1): per node, exclusive prefix over stripe counts ->
// p[s][n] (u16, bounded by degree); total -> deg_i[n]; tile sums -> bsums.
// ---------------------------------------------------------------------------
__global__ __launch_bounds__(1024) void reduce_kernel(
    const unsigned short* __restrict__ h, unsigned short* __restrict__ p,
    int* __restrict__ deg_i, int* __restrict__ bsums)
{
    __shared__ int sred[1024];
    int t = threadIdx.x;
    int n = blockIdx.x * 1024 + t;
    int run = 0;
    if (n < N_NODES_C) {
        #pragma unroll 8
        for (int s = 0; s < S_STRIPES; ++s) {
            int c = h[(size_t)s * N_NODES_C + n];
            p[(size_t)s * N_NODES_C + n] = (unsigned short)run;
            run += c;
        }
        deg_i[n] = run;
    }
    sred[t] = (n < N_NODES_C) ? run : 0;
    __syncthreads();
    for (int o = 512; o > 0; o >>= 1) {
        if (t < o) sred[t] += sred[t + o];
        __syncthreads();
    }
    if (t == 0) bsums[blockIdx.x] = sred[0];
}

// scan3: tile-prefix via wave-reduce of bsums + intra-tile exclusive scan
__global__ __launch_bounds__(256) void scan3_kernel(
    const int* __restrict__ deg_i, const int* __restrict__ bsums,
    int* __restrict__ off, int n)
{
    __shared__ int s[256];
    __shared__ int sbp;
    int b = blockIdx.x;
    int t = threadIdx.x;
    if (t < 64) {
        int v = (t < b) ? bsums[t] : 0;      // b <= 48 < 64
        #pragma unroll
        for (int m = 1; m < 64; m <<= 1) v += __shfl_xor(v, m, 64);
        if (t == 0) sbp = v;
    }
    int base = b * SCAN_TILE;
    int v4[4];
    int sum = 0;
    #pragma unroll
    for (int j = 0; j < 4; ++j) {
        int i = base + t * 4 + j;
        v4[j] = (i < n) ? deg_i[i] : 0;
        sum += v4[j];
    }
    s[t] = sum;
    __syncthreads();
    for (int o = 1; o < 256; o <<= 1) {
        int tmp = (t >= o) ? s[t - o] : 0;
        __syncthreads();
        s[t] += tmp;
        __syncthreads();
    }
    int run = s[t] - sum + sbp;
    #pragma unroll
    for (int j = 0; j < 4; ++j) {
        int i = base + t * 4 + j;
        if (i < n) off[i] = run;
        run += v4[j];
    }
    if (b == N_SCAN_BLK - 1 && t == 255) off[n] = sbp + s[255];
}

// ---------------------------------------------------------------------------
// scatter2d: block (s,r) places stripe-s edges of range r via LDS cursors
// seeded with off[d] + p[s][d]. Unique slots -> plain stores, zero global
// atomics. Grid 512 = 2 blocks/CU.
// ---------------------------------------------------------------------------
__global__ __launch_bounds__(1024) void scatter2d_kernel(
    const int* __restrict__ src, const int* __restrict__ dst,
    const int* __restrict__ off, const unsigned short* __restrict__ p,
    int* __restrict__ adj, int n_edges, int stripe)
{
    __shared__ int lcur[RANGE_SZ];
    int s = blockIdx.x >> 3, r = blockIdx.x & 7;
    int lo = r * RANGE_SZ;
    int t = threadIdx.x;
    for (int i = t; i < RANGE_SZ; i += 1024)
        lcur[i] = off[lo + i] + (int)p[(size_t)s * N_NODES_C + lo + i];
    __syncthreads();
    int e1 = min(n_edges, (s + 1) * stripe);
    #pragma unroll 4
    for (int e = s * stripe + t; e < e1; e += 1024) {
        int d = dst[e] - lo;
        if ((unsigned)d < (unsigned)RANGE_SZ) {
            int pos = atomicAdd(&lcur[d], 1);
            adj[pos] = src[e];
        }
    }
}

// ---------------------------------------------------------------------------
// Gather-mean (round-11 proven form): one wave per node, TWO edges per load
// instr (lanes 0-31 = even edge row, 32-63 = odd edge row), 8-edge granule.
// Fold halves with one shfl_xor(32). Source = 6.4MB, ~L2-resident.
// ---------------------------------------------------------------------------
__global__ __launch_bounds__(256) void gather_mean_kernel(
    const unsigned* __restrict__ xh,
    const int* __restrict__ adj,
    const int* __restrict__ off,
    unsigned* __restrict__ agg)
{
    int t = threadIdx.x;
    int wave = t >> 6, lane = t & 63;
    int node = blockIdx.x * 4 + wave;     // 12500 blocks * 4 = 50000 exact
    int o = off[node];
    int d = off[node + 1] - o;
    int half = lane >> 5;
    int col = lane & 31;
    float sx = 0.f, sy = 0.f;

    for (int j0 = 0; j0 < d; j0 += 64) {
        int c = d - j0; if (c > 64) c = 64;
        int nid = (lane < c) ? adj[o + j0 + lane] : 0;
        int j = 0;
        for (; j + 8 <= c; j += 8) {
            #pragma unroll
            for (int m = 0; m < 4; ++m) {
                int re = bl_i(nid, j + 2 * m);
                int ro = bl_i(nid, j + 2 * m + 1);
                int row = half ? ro : re;
                unsigned u = xh[(size_t)row * 32 + col];
                sx += uf(u << 16); sy += uf(u & 0xFFFF0000u);
            }
        }
        for (; j < c; j += 2) {
            int re = bl_i(nid, j);
            int ro = (j + 1 < c) ? bl_i(nid, j + 1) : re;
            int row = half ? ro : re;
            unsigned u = xh[(size_t)row * 32 + col];
            if (half && j + 1 >= c) u = 0u;
            sx += uf(u << 16); sy += uf(u & 0xFFFF0000u);
        }
    }
    sx += __shfl_xor(sx, 32, 64);
    sy += __shfl_xor(sy, 32, 64);
    if (half == 0) {
        float inv = 1.0f / fmaxf((float)d, 1.0f);
        agg[(size_t)node * 32 + col] = pk_bf16(sx * inv, sy * inv);
    }
}

// ---------------------------------------------------------------------------
// MFMA GEMM: emb = [x | agg] @ [[Ws],[Wn]] + b  (M=50000, K=128, N=128).
// W packed bf16-K-pairs in LDS ([64][129] u32, padded vs bank aliasing).
// ---------------------------------------------------------------------------
__global__ __launch_bounds__(256) void gemm_kernel(
    const unsigned* __restrict__ xh,
    const unsigned* __restrict__ agg,
    const float* __restrict__ Wn,
    const float* __restrict__ Ws,
    const float* __restrict__ bias,
    float* __restrict__ emb_out)
{
    __shared__ unsigned sWk[64 * 129];   // sWk[kk][n] = pack(Wf[2kk][n], Wf[2kk+1][n])
    __shared__ float sb[128];
    int t = threadIdx.x;
    for (int e = t; e < 64 * 128; e += 256) {
        int kk = e >> 7, n = e & 127;
        float w0, w1;
        if (kk < 32) { w0 = Ws[(2 * kk) * 128 + n];      w1 = Ws[(2 * kk + 1) * 128 + n]; }
        else         { w0 = Wn[(2 * kk - 64) * 128 + n]; w1 = Wn[(2 * kk - 63) * 128 + n]; }
        sWk[kk * 129 + n] = pk_bf16(w0, w1);
    }
    if (t < 128) sb[t] = bias[t];
    __syncthreads();

    int wave = t >> 6, lane = t & 63;
    int lr = lane & 15, lg = lane >> 4;
    int tile = blockIdx.x * 4 + wave;
    if (tile >= N_TILES) return;

    const uint4* xr = (const uint4*)(xh + ((size_t)tile * 16 + lr) * 32);
    const uint4* ar = (const uint4*)(agg + ((size_t)tile * 16 + lr) * 32);
    U8 A[4];
    A[0].q = xr[lg];
    A[1].q = xr[4 + lg];
    A[2].q = ar[lg];
    A[3].q = ar[4 + lg];

    #pragma unroll
    for (int c = 0; c < 8; ++c) {
        float bv = sb[c * 16 + lr];
        f32x4 acc = {bv, bv, bv, bv};
        #pragma unroll
        for (int s = 0; s < 4; ++s) {
            U8 B;
            #pragma unroll
            for (int jj = 0; jj < 4; ++jj)
                B.u[jj] = sWk[(16 * s + 4 * lg + jj) * 129 + c * 16 + lr];
            acc = __builtin_amdgcn_mfma_f32_16x16x32_bf16(A[s].s, B.s, acc, 0, 0, 0);
        }
        #pragma unroll
        for (int r = 0; r < 4; ++r)
            emb_out[((size_t)tile * 16 + lg * 4 + r) * 128 + c * 16 + lr] = acc[r];
    }
}

// ---------------------------------------------------------------------------
// Fused segment mean-pool of relu(emb) + MLP head + log_softmax.
// ---------------------------------------------------------------------------
__global__ __launch_bounds__(256) void poolhead_kernel(
    const float* __restrict__ emb, const int* __restrict__ start,
    const float* __restrict__ W1, const float* __restrict__ b1,
    const float* __restrict__ W2, const float* __restrict__ b2,
    float* __restrict__ logits_out)
{
    int g = blockIdx.x;
    int t = threadIdx.x;
    __shared__ float sp[HID_C];
    __shared__ float shid[MLP_HID_C];
    __shared__ float sl[N_CLS_C];
    __shared__ float4 red[256];

    int s0 = start[g], e0 = start[g + 1];
    int q = t & 31, r0 = t >> 5;
    const float4* e4 = (const float4*)emb;
    float4 acc = make_float4(0.f, 0.f, 0.f, 0.f);
    for (int r = s0 + r0; r < e0; r += 8) {
        float4 v = e4[(size_t)r * 32 + q];
        acc.x += fmaxf(v.x, 0.f); acc.y += fmaxf(v.y, 0.f);
        acc.z += fmaxf(v.z, 0.f); acc.w += fmaxf(v.w, 0.f);
    }
    red[t] = acc;
    __syncthreads();
    if (t < 32) {
        float4 a = red[t];
        #pragma unroll
        for (int r = 1; r < 8; ++r) {
            float4 b = red[t + 32 * r];
            a.x += b.x; a.y += b.y; a.z += b.z; a.w += b.w;
        }
        float inv = 1.0f / fmaxf((float)(e0 - s0), 1.0f);
        ((float4*)sp)[t] = make_float4(a.x * inv, a.y * inv, a.z * inv, a.w * inv);
    }
    __syncthreads();

    if (t < MLP_HID_C) {
        float a = b1[t];
        #pragma unroll 8
        for (int k = 0; k < HID_C; ++k) a += sp[k] * W1[k * MLP_HID_C + t];
        shid[t] = fmaxf(a, 0.0f);
    }
    __syncthreads();

    if (t < N_CLS_C) {
        float a = b2[t];
        #pragma unroll
        for (int k = 0; k < MLP_HID_C; ++k) a += shid[k] * W2[k * N_CLS_C + t];
        sl[t] = a;
    }
    __syncthreads();

    if (t < N_CLS_C) {
        float m = sl[0];
        #pragma unroll
        for (int i = 1; i < N_CLS_C; ++i) m = fmaxf(m, sl[i]);
        float sum = 0.0f;
        #pragma unroll
        for (int i = 0; i < N_CLS_C; ++i) sum += expf(sl[i] - m);
        logits_out[(size_t)g * N_CLS_C + t] = sl[t] - m - logf(sum);
    }
}

extern "C" void kernel_launch(void* const* d_in, const int* in_sizes, int n_in,
                              void* d_out, int out_size, void* d_ws, size_t ws_size,
                              hipStream_t stream) {
    const float* x      = (const float*)d_in[0];
    const int*   ei     = (const int*)d_in[1];
    const int*   batch  = (const int*)d_in[2];
    const float* Wn     = (const float*)d_in[3];
    const float* Ws     = (const float*)d_in[4];
    const float* bias   = (const float*)d_in[5];
    const float* W1     = (const float*)d_in[6];
    const float* b1     = (const float*)d_in[7];
    const float* W2     = (const float*)d_in[8];
    const float* b2     = (const float*)d_in[9];

    float* out = (float*)d_out;
    int n_edges = in_sizes[1] / 2;
    const int* src = ei;
    const int* dst = ei + n_edges;
    int stripe = (n_edges + S_STRIPES - 1) / S_STRIPES;

    // ws (ints): deg_i[N] | off[N+1] | bsums[64] | start[G+1] | pad[2] |
    //            xh[(N+1)*32] | adj[E(pad4)] | agg[N*32] | h[S*N u16] | p[S*N u16]
    int* deg_i   = (int*)d_ws;
    int* off     = deg_i + N_NODES_C;
    int* bsums   = off + (N_NODES_C + 1);
    int* start   = bsums + 64;
    unsigned* xh = (unsigned*)(start + (N_GRAPHS_C + 1) + 2);   // 16B-aligned
    int* adj     = (int*)(xh + (size_t)(N_NODES_C + 1) * 32);
    unsigned* agg = (unsigned*)(adj + ((n_edges + 3) & ~3));
    unsigned short* h = (unsigned short*)(agg + (size_t)N_NODES_C * 32);
    unsigned short* p = h + (size_t)S_STRIPES * N_NODES_C;

    hist2d_kernel<<<S_STRIPES * N_RANGES, 1024, 0, stream>>>(dst, x, batch, xh,
                                                             start, h, n_edges, stripe);
    reduce_kernel<<<N_SCAN_BLK, 1024, 0, stream>>>(h, p, deg_i, bsums);
    scan3_kernel<<<N_SCAN_BLK, 256, 0, stream>>>(deg_i, bsums, off, N_NODES_C);
    scatter2d_kernel<<<S_STRIPES * N_RANGES, 1024, 0, stream>>>(src, dst, off, p,
                                                                adj, n_edges, stripe);

    gather_mean_kernel<<<12500, 256, 0, stream>>>(xh, adj, off, agg);

    gemm_kernel<<<782, 256, 0, stream>>>(xh, agg, Wn, Ws, bias, out);

    poolhead_kernel<<<N_GRAPHS_C, 256, 0, stream>>>(out, start, W1, b1, W2, b2,
                                                    out + (size_t)N_NODES_C * HID_C);
}

// Round 17
// 88.002 us; speedup vs baseline: 1.1339x; 1.0016x over previous
//
#include <hip/hip_runtime.h>

#define N_NODES_C 50000
#define F_IN_C 64
#define HID_C 128
#define N_GRAPHS_C 500
#define N_CLS_C 10
#define MLP_HID_C 50
#define SCAN_TILE 1024
#define N_SCAN_BLK ((N_NODES_C + SCAN_TILE - 1) / SCAN_TILE)   // 49
#define N_TILES (N_NODES_C / 16)                               // 3125
#define N_RANGES 8
#define RANGE_SZ (N_NODES_C / N_RANGES)                        // 6250 (exact)
#define S_STRIPES 64

using short8 = __attribute__((ext_vector_type(8))) short;
using f32x4  = __attribute__((ext_vector_type(4))) float;

__device__ __forceinline__ int bl_i(int v, int l) {
    return __builtin_amdgcn_readlane(v, l);
}
__device__ __forceinline__ float uf(unsigned u) { return __uint_as_float(u); }

// round-to-nearest-even bf16 pack of two floats -> (lo=a, hi=b)
__device__ __forceinline__ unsigned pk_bf16(float a, float b) {
    unsigned ua = __float_as_uint(a), ub = __float_as_uint(b);
    ua += 0x7FFFu + ((ua >> 16) & 1u);
    ub += 0x7FFFu + ((ub >> 16) & 1u);
    return (ua >> 16) | (ub & 0xFFFF0000u);
}

union U8 { unsigned u[4]; uint4 q; short8 s; };

// ---------------------------------------------------------------------------
// hist2d + fused prep: block (s,r) builds an LDS histogram of node-range r
// over edge-stripe s (no global atomics); h stored u16 (counts <= stripe).
// Between hist phases the grid streams prep (bf16 x + zero row, bounds).
// ---------------------------------------------------------------------------
__global__ __launch_bounds__(1024) void hist2d_kernel(
    const int* __restrict__ dst,
    const float* __restrict__ x,
    const int* __restrict__ batch,
    unsigned* __restrict__ xh,
    int* __restrict__ start,
    unsigned short* __restrict__ h,
    int n_edges, int stripe)
{
    __shared__ int lh[RANGE_SZ];
    int s = blockIdx.x >> 3, r = blockIdx.x & 7;
    int lo = r * RANGE_SZ;
    int t = threadIdx.x;
    for (int i = t; i < RANGE_SZ; i += 1024) lh[i] = 0;
    __syncthreads();
    int e1 = min(n_edges, (s + 1) * stripe);
    #pragma unroll 4
    for (int e = s * stripe + t; e < e1; e += 1024) {
        int d = dst[e] - lo;
        if ((unsigned)d < (unsigned)RANGE_SZ) atomicAdd(&lh[d], 1);
    }

    // fused prep (grid-stride across all 512 blocks)
    int tid = blockIdx.x * 1024 + t;
    int stride = gridDim.x * 1024;
    const float2* xf2 = (const float2*)x;
    int nx = N_NODES_C * (F_IN_C / 2);
    int total = (N_NODES_C + 1) * (F_IN_C / 2);
    for (int i = tid; i < total; i += stride) {
        if (i < nx) { float2 v = xf2[i]; xh[i] = pk_bf16(v.x, v.y); }
        else        xh[i] = 0u;
    }
    for (int i = tid; i < N_NODES_C; i += stride) {
        int b = batch[i];
        if (i == 0) { for (int g = 0; g <= b; ++g) start[g] = 0; }
        else { int p = batch[i - 1]; for (int g = p + 1; g <= b; ++g) start[g] = i; }
        if (i == N_NODES_C - 1) { for (int g = b + 1; g <= N_GRAPHS_C; ++g) start[g] = N_NODES_C; }
    }

    __syncthreads();
    for (int i = t; i < RANGE_SZ; i += 1024)
        h[(size_t)s * N_NODES_C + lo + i] = (unsigned short)lh[i];
}

// ---------------------------------------------------------------------------
// reduce (+ fused scan1): per node, exclusive prefix over stripe counts ->
// p[s][n] (u16, bounded by degree); total -> deg_i[n]; tile sums -> bsums.
// ---------------------------------------------------------------------------
__global__ __launch_bounds__(1024) void reduce_kernel(
    const unsigned short* __restrict__ h, unsigned short* __restrict__ p,
    int* __restrict__ deg_i, int* __restrict__ bsums)
{
    __shared__ int sred[1024];
    int t = threadIdx.x;
    int n = blockIdx.x * 1024 + t;
    int run = 0;
    if (n < N_NODES_C) {
        #pragma unroll 8
        for (int s = 0; s < S_STRIPES; ++s) {
            int c = h[(size_t)s * N_NODES_C + n];
            p[(size_t)s * N_NODES_C + n] = (unsigned short)run;
            run += c;
        }
        deg_i[n] = run;
    }
    sred[t] = (n < N_NODES_C) ? run : 0;
    __syncthreads();
    for (int o = 512; o > 0; o >>= 1) {
        if (t < o) sred[t] += sred[t + o];
        __syncthreads();
    }
    if (t == 0) bsums[blockIdx.x] = sred[0];
}

// scan3: tile-prefix via wave-reduce of bsums + intra-tile exclusive scan
__global__ __launch_bounds__(256) void scan3_kernel(
    const int* __restrict__ deg_i, const int* __restrict__ bsums,
    int* __restrict__ off, int n)
{
    __shared__ int s[256];
    __shared__ int sbp;
    int b = blockIdx.x;
    int t = threadIdx.x;
    if (t < 64) {
        int v = (t < b) ? bsums[t] : 0;      // b <= 48 < 64
        #pragma unroll
        for (int m = 1; m < 64; m <<= 1) v += __shfl_xor(v, m, 64);
        if (t == 0) sbp = v;
    }
    int base = b * SCAN_TILE;
    int v4[4];
    int sum = 0;
    #pragma unroll
    for (int j = 0; j < 4; ++j) {
        int i = base + t * 4 + j;
        v4[j] = (i < n) ? deg_i[i] : 0;
        sum += v4[j];
    }
    s[t] = sum;
    __syncthreads();
    for (int o = 1; o < 256; o <<= 1) {
        int tmp = (t >= o) ? s[t - o] : 0;
        __syncthreads();
        s[t] += tmp;
        __syncthreads();
    }
    int run = s[t] - sum + sbp;
    #pragma unroll
    for (int j = 0; j < 4; ++j) {
        int i = base + t * 4 + j;
        if (i < n) off[i] = run;
        run += v4[j];
    }
    if (b == N_SCAN_BLK - 1 && t == 255) off[n] = sbp + s[255];
}

// ---------------------------------------------------------------------------
// scatter2d: block (s,r) places stripe-s edges of range r via LDS cursors
// seeded with off[d] + p[s][d]. Unique slots -> plain stores, zero global
// atomics. Grid 512 = 2 blocks/CU.
// ---------------------------------------------------------------------------
__global__ __launch_bounds__(1024) void scatter2d_kernel(
    const int* __restrict__ src, const int* __restrict__ dst,
    const int* __restrict__ off, const unsigned short* __restrict__ p,
    int* __restrict__ adj, int n_edges, int stripe)
{
    __shared__ int lcur[RANGE_SZ];
    int s = blockIdx.x >> 3, r = blockIdx.x & 7;
    int lo = r * RANGE_SZ;
    int t = threadIdx.x;
    for (int i = t; i < RANGE_SZ; i += 1024)
        lcur[i] = off[lo + i] + (int)p[(size_t)s * N_NODES_C + lo + i];
    __syncthreads();
    int e1 = min(n_edges, (s + 1) * stripe);
    #pragma unroll 4
    for (int e = s * stripe + t; e < e1; e += 1024) {
        int d = dst[e] - lo;
        if ((unsigned)d < (unsigned)RANGE_SZ) {
            int pos = atomicAdd(&lcur[d], 1);
            adj[pos] = src[e];
        }
    }
}

// ---------------------------------------------------------------------------
// Gather-mean (proven form): one wave per node, TWO edges per load instr
// (lanes 0-31 = even edge row, 32-63 = odd edge row), 8-edge granule.
// Fold halves with one shfl_xor(32). Source = 6.4MB, ~L2-resident.
// ---------------------------------------------------------------------------
__global__ __launch_bounds__(256) void gather_mean_kernel(
    const unsigned* __restrict__ xh,
    const int* __restrict__ adj,
    const int* __restrict__ off,
    unsigned* __restrict__ agg)
{
    int t = threadIdx.x;
    int wave = t >> 6, lane = t & 63;
    int node = blockIdx.x * 4 + wave;     // 12500 blocks * 4 = 50000 exact
    int o = off[node];
    int d = off[node + 1] - o;
    int half = lane >> 5;
    int col = lane & 31;
    float sx = 0.f, sy = 0.f;

    for (int j0 = 0; j0 < d; j0 += 64) {
        int c = d - j0; if (c > 64) c = 64;
        int nid = (lane < c) ? adj[o + j0 + lane] : 0;
        int j = 0;
        for (; j + 8 <= c; j += 8) {
            #pragma unroll
            for (int m = 0; m < 4; ++m) {
                int re = bl_i(nid, j + 2 * m);
                int ro = bl_i(nid, j + 2 * m + 1);
                int row = half ? ro : re;
                unsigned u = xh[(size_t)row * 32 + col];
                sx += uf(u << 16); sy += uf(u & 0xFFFF0000u);
            }
        }
        for (; j < c; j += 2) {
            int re = bl_i(nid, j);
            int ro = (j + 1 < c) ? bl_i(nid, j + 1) : re;
            int row = half ? ro : re;
            unsigned u = xh[(size_t)row * 32 + col];
            if (half && j + 1 >= c) u = 0u;
            sx += uf(u << 16); sy += uf(u & 0xFFFF0000u);
        }
    }
    sx += __shfl_xor(sx, 32, 64);
    sy += __shfl_xor(sy, 32, 64);
    if (half == 0) {
        float inv = 1.0f / fmaxf((float)d, 1.0f);
        agg[(size_t)node * 32 + col] = pk_bf16(sx * inv, sy * inv);
    }
}

// ---------------------------------------------------------------------------
// MFMA GEMM: emb = [x | agg] @ [[Ws],[Wn]] + b  (M=50000, K=128, N=128).
// W packed bf16-K-pairs in LDS ([64][129] u32, padded vs bank aliasing).
// ---------------------------------------------------------------------------
__global__ __launch_bounds__(256) void gemm_kernel(
    const unsigned* __restrict__ xh,
    const unsigned* __restrict__ agg,
    const float* __restrict__ Wn,
    const float* __restrict__ Ws,
    const float* __restrict__ bias,
    float* __restrict__ emb_out)
{
    __shared__ unsigned sWk[64 * 129];   // sWk[kk][n] = pack(Wf[2kk][n], Wf[2kk+1][n])
    __shared__ float sb[128];
    int t = threadIdx.x;
    for (int e = t; e < 64 * 128; e += 256) {
        int kk = e >> 7, n = e & 127;
        float w0, w1;
        if (kk < 32) { w0 = Ws[(2 * kk) * 128 + n];      w1 = Ws[(2 * kk + 1) * 128 + n]; }
        else         { w0 = Wn[(2 * kk - 64) * 128 + n]; w1 = Wn[(2 * kk - 63) * 128 + n]; }
        sWk[kk * 129 + n] = pk_bf16(w0, w1);
    }
    if (t < 128) sb[t] = bias[t];
    __syncthreads();

    int wave = t >> 6, lane = t & 63;
    int lr = lane & 15, lg = lane >> 4;
    int tile = blockIdx.x * 4 + wave;
    if (tile >= N_TILES) return;

    const uint4* xr = (const uint4*)(xh + ((size_t)tile * 16 + lr) * 32);
    const uint4* ar = (const uint4*)(agg + ((size_t)tile * 16 + lr) * 32);
    U8 A[4];
    A[0].q = xr[lg];
    A[1].q = xr[4 + lg];
    A[2].q = ar[lg];
    A[3].q = ar[4 + lg];

    #pragma unroll
    for (int c = 0; c < 8; ++c) {
        float bv = sb[c * 16 + lr];
        f32x4 acc = {bv, bv, bv, bv};
        #pragma unroll
        for (int s = 0; s < 4; ++s) {
            U8 B;
            #pragma unroll
            for (int jj = 0; jj < 4; ++jj)
                B.u[jj] = sWk[(16 * s + 4 * lg + jj) * 129 + c * 16 + lr];
            acc = __builtin_amdgcn_mfma_f32_16x16x32_bf16(A[s].s, B.s, acc, 0, 0, 0);
        }
        #pragma unroll
        for (int r = 0; r < 4; ++r)
            emb_out[((size_t)tile * 16 + lg * 4 + r) * 128 + c * 16 + lr] = acc[r];
    }
}

// ---------------------------------------------------------------------------
// Fused segment mean-pool of relu(emb) + MLP head + log_softmax.
// ---------------------------------------------------------------------------
__global__ __launch_bounds__(256) void poolhead_kernel(
    const float* __restrict__ emb, const int* __restrict__ start,
    const float* __restrict__ W1, const float* __restrict__ b1,
    const float* __restrict__ W2, const float* __restrict__ b2,
    float* __restrict__ logits_out)
{
    int g = blockIdx.x;
    int t = threadIdx.x;
    __shared__ float sp[HID_C];
    __shared__ float shid[MLP_HID_C];
    __shared__ float sl[N_CLS_C];
    __shared__ float4 red[256];

    int s0 = start[g], e0 = start[g + 1];
    int q = t & 31, r0 = t >> 5;
    const float4* e4 = (const float4*)emb;
    float4 acc = make_float4(0.f, 0.f, 0.f, 0.f);
    for (int r = s0 + r0; r < e0; r += 8) {
        float4 v = e4[(size_t)r * 32 + q];
        acc.x += fmaxf(v.x, 0.f); acc.y += fmaxf(v.y, 0.f);
        acc.z += fmaxf(v.z, 0.f); acc.w += fmaxf(v.w, 0.f);
    }
    red[t] = acc;
    __syncthreads();
    if (t < 32) {
        float4 a = red[t];
        #pragma unroll
        for (int r = 1; r < 8; ++r) {
            float4 b = red[t + 32 * r];
            a.x += b.x; a.y += b.y; a.z += b.z; a.w += b.w;
        }
        float inv = 1.0f / fmaxf((float)(e0 - s0), 1.0f);
        ((float4*)sp)[t] = make_float4(a.x * inv, a.y * inv, a.z * inv, a.w * inv);
    }
    __syncthreads();

    if (t < MLP_HID_C) {
        float a = b1[t];
        #pragma unroll 8
        for (int k = 0; k < HID_C; ++k) a += sp[k] * W1[k * MLP_HID_C + t];
        shid[t] = fmaxf(a, 0.0f);
    }
    __syncthreads();

    if (t < N_CLS_C) {
        float a = b2[t];
        #pragma unroll
        for (int k = 0; k < MLP_HID_C; ++k) a += shid[k] * W2[k * N_CLS_C + t];
        sl[t] = a;
    }
    __syncthreads();

    if (t < N_CLS_C) {
        float m = sl[0];
        #pragma unroll
        for (int i = 1; i < N_CLS_C; ++i) m = fmaxf(m, sl[i]);
        float sum = 0.0f;
        #pragma unroll
        for (int i = 0; i < N_CLS_C; ++i) sum += expf(sl[i] - m);
        logits_out[(size_t)g * N_CLS_C + t] = sl[t] - m - logf(sum);
    }
}

extern "C" void kernel_launch(void* const* d_in, const int* in_sizes, int n_in,
                              void* d_out, int out_size, void* d_ws, size_t ws_size,
                              hipStream_t stream) {
    const float* x      = (const float*)d_in[0];
    const int*   ei     = (const int*)d_in[1];
    const int*   batch  = (const int*)d_in[2];
    const float* Wn     = (const float*)d_in[3];
    const float* Ws     = (const float*)d_in[4];
    const float* bias   = (const float*)d_in[5];
    const float* W1     = (const float*)d_in[6];
    const float* b1     = (const float*)d_in[7];
    const float* W2     = (const float*)d_in[8];
    const float* b2     = (const float*)d_in[9];

    float* out = (float*)d_out;
    int n_edges = in_sizes[1] / 2;
    const int* src = ei;
    const int* dst = ei + n_edges;
    int stripe = (n_edges + S_STRIPES - 1) / S_STRIPES;

    // ws (ints): deg_i[N] | off[N+1] | bsums[64] | start[G+1] | pad[2] |
    //            xh[(N+1)*32] | adj[E(pad4)] | agg[N*32] | h[S*N u16] | p[S*N u16]
    int* deg_i   = (int*)d_ws;
    int* off     = deg_i + N_NODES_C;
    int* bsums   = off + (N_NODES_C + 1);
    int* start   = bsums + 64;
    unsigned* xh = (unsigned*)(start + (N_GRAPHS_C + 1) + 2);   // 16B-aligned
    int* adj     = (int*)(xh + (size_t)(N_NODES_C + 1) * 32);
    unsigned* agg = (unsigned*)(adj + ((n_edges + 3) & ~3));
    unsigned short* h = (unsigned short*)(agg + (size_t)N_NODES_C * 32);
    unsigned short* p = h + (size_t)S_STRIPES * N_NODES_C;

    hist2d_kernel<<<S_STRIPES * N_RANGES, 1024, 0, stream>>>(dst, x, batch, xh,
                                                             start, h, n_edges, stripe);
    reduce_kernel<<<N_SCAN_BLK, 1024, 0, stream>>>(h, p, deg_i, bsums);
    scan3_kernel<<<N_SCAN_BLK, 256, 0, stream>>>(deg_i, bsums, off, N_NODES_C);
    scatter2d_kernel<<<S_STRIPES * N_RANGES, 1024, 0, stream>>>(src, dst, off, p,
                                                                adj, n_edges, stripe);

    gather_mean_kernel<<<12500, 256, 0, stream>>>(xh, adj, off, agg);

    gemm_kernel<<<782, 256, 0, stream>>>(xh, agg, Wn, Ws, bias, out);

    poolhead_kernel<<<N_GRAPHS_C, 256, 0, stream>>>(out, start, W1, b1, W2, b2,
                                                    out + (size_t)N_NODES_C * HID_C);
}